// Round 13
// baseline (2720.983 us; speedup 1.0000x reference)
//
#include <hip/hip_runtime.h>
#include <hip/hip_bf16.h>

#define D 4096
#define NH 32
#define NKV 8
#define HD 128
#define FF 14336
#define VOC 1024
#define TT 32
#define GENN 8
#define SEQ 9

#define NQKV 6144   // fused QKV cols: 4096 Q + 1024 K + 1024 V
#define NGU  28672  // fused gate+up cols

// workspace offsets (floats)
#define OFF_BUF   0ull
#define OFF_KC    1179648ull
#define OFF_VC    1474560ull
#define OFF_AOT   1769472ull
#define OFF_XP    1900544ull
#define OFF_R1    2031616ull
#define OFF_R2    2031680ull
#define OFF_XPK   2031744ull
#define OFF_PART  2490496ull
#define OFF_RED   6684800ull   // NQKV*TT reduced QKV
#define OFF_LR    6881408ull   // VOC*TT reduced logits
#define OFF_PACK  6914176ull   // packed-W region (dwords)
// packed sub-offsets (dwords from OFF_PACK)
#define PK_QKV 0ull
#define PK_WO  25165824ull
#define PK_GU  41943040ull
#define PK_WD  159383552ull
#define PK_OUT 218103808ull
#define PK_TOTAL 222298112ull

typedef __attribute__((ext_vector_type(8))) short short8;
typedef __attribute__((ext_vector_type(16))) float f32x16;
typedef __attribute__((address_space(1))) void gv_t;
typedef __attribute__((address_space(3))) void lv_t;

__device__ inline void cvt_hi_lo(const float* x, short8& hi, short8& lo) {
    union U { unsigned u[4]; short8 s; };
    U H, L;
    #pragma unroll
    for (int j = 0; j < 4; ++j) {
        float2 p = make_float2(x[2 * j], x[2 * j + 1]);
        __hip_bfloat162 h = __float22bfloat162_rn(p);
        unsigned hb; __builtin_memcpy(&hb, &h, 4);
        H.u[j] = hb;
        float f0 = __uint_as_float(hb << 16);
        float f1 = __uint_as_float(hb & 0xffff0000u);
        __hip_bfloat162 l = __float22bfloat162_rn(make_float2(p.x - f0, p.y - f1));
        unsigned lb; __builtin_memcpy(&lb, &l, 4);
        L.u[j] = lb;
    }
    hi = H.s; lo = L.s;
}

__device__ inline void store_frag(unsigned* Xp, int frag, int lane,
                                  const short8& hi, const short8& lo) {
    unsigned* dst = Xp + (size_t)frag * 512 + lane * 4;
    union U { short8 s; uint4 u; };
    U uh, ul; uh.s = hi; ul.s = lo;
    *(uint4*)dst = uh.u;
    *(uint4*)(dst + 256) = ul.u;
}

__global__ void k_init(const float* __restrict__ x0, float* __restrict__ buf,
                       float* __restrict__ r1) {
    int t = blockIdx.x;
    const float* src = x0 + (size_t)t * D;
    float* dst = buf + (size_t)t * SEQ * D;
    float ss = 0.f;
    for (int d = threadIdx.x; d < D; d += 256) { float v = src[d]; dst[d] = v; ss += v * v; }
    #pragma unroll
    for (int m = 1; m < 64; m <<= 1) ss += __shfl_xor(ss, m);
    __shared__ float red[4];
    if ((threadIdx.x & 63) == 0) red[threadIdx.x >> 6] = ss;
    __syncthreads();
    if (threadIdx.x == 0) {
        float tot = red[0] + red[1] + red[2] + red[3];
        r1[t] = 1.0f / sqrtf(tot / (float)D + 1e-5f);
    }
}

__global__ void k_rms_rows(const float* __restrict__ x, float* __restrict__ r) {
    int t = blockIdx.x;
    const float* row = x + (size_t)t * D;
    float ss = 0.f;
    for (int d = threadIdx.x; d < D; d += 256) { float v = row[d]; ss += v * v; }
    #pragma unroll
    for (int m = 1; m < 64; m <<= 1) ss += __shfl_xor(ss, m);
    __shared__ float red[4];
    if ((threadIdx.x & 63) == 0) red[threadIdx.x >> 6] = ss;
    __syncthreads();
    if (threadIdx.x == 0) {
        float tot = red[0] + red[1] + red[2] + red[3];
        r[t] = 1.0f / sqrtf(tot / (float)D + 1e-5f);
    }
}

__global__ __launch_bounds__(256) void k_pack_norm(const float* __restrict__ src0,
        int rowStride, const float* __restrict__ r, const float* __restrict__ w,
        unsigned* __restrict__ Xp) {
    int frag = blockIdx.x * 4 + (threadIdx.x >> 6);
    int lane = threadIdx.x & 63;
    int m = lane & 31, half = lane >> 5;
    int k0 = frag * 16 + half * 8;
    const float* src = src0 + (size_t)m * rowStride + k0;
    float rr = r[m];
    float x[8];
    #pragma unroll
    for (int e = 0; e < 8; ++e) x[e] = src[e] * rr * w[k0 + e];
    short8 hi, lo; cvt_hi_lo(x, hi, lo); store_frag(Xp, frag, lane, hi, lo);
}

__global__ __launch_bounds__(256) void k_pack(const float* __restrict__ XT,
                                              unsigned* __restrict__ Xp) {
    int frag = blockIdx.x * 4 + (threadIdx.x >> 6);
    int lane = threadIdx.x & 63;
    int m = lane & 31, half = lane >> 5;
    const float* src = XT + (size_t)(frag * 16 + half * 8) * TT + m;
    float x[8];
    #pragma unroll
    for (int e = 0; e < 8; ++e) x[e] = src[e * TT];
    short8 hi, lo; cvt_hi_lo(x, hi, lo); store_frag(Xp, frag, lane, hi, lo);
}

// ---- one-time weight repack into phase-contiguous MFMA-A fragment layout ----
__global__ __launch_bounds__(256) void k_pack_w(const float* __restrict__ W,
        unsigned* __restrict__ dst, int K, int kc, int nph, int ntiles,
        int rowsBase, int nRowTiles) {
    int b = blockIdx.x;
    int ph = b % nph; int rest = b / nph;
    int tLoc = rest % nRowTiles; int s = rest / nRowTiles;
    int kbase = s * kc + ph * 32;
    __shared__ float lds[128][33];
    int t = threadIdx.x;
    int r = t >> 1, c0 = (t & 1) * 16;
    const float* src = W + (size_t)(tLoc * 128 + r) * K + kbase + c0;
    #pragma unroll
    for (int j = 0; j < 16; j += 4) {
        float4 v = *(const float4*)(src + j);
        lds[r][c0 + j] = v.x; lds[r][c0 + j + 1] = v.y;
        lds[r][c0 + j + 2] = v.z; lds[r][c0 + j + 3] = v.w;
    }
    __syncthreads();
    size_t blk = (size_t)s * ntiles + rowsBase + tLoc;
    #pragma unroll
    for (int fid = t; fid < 512; fid += 256) {
        int lane = fid & 63, step = (fid >> 6) & 1, wv = fid >> 7;
        int m = lane & 31, half = lane >> 5;
        int row = wv * 32 + m;
        int kl = step * 16 + half * 8;
        float x[8];
        #pragma unroll
        for (int e = 0; e < 8; ++e) x[e] = lds[row][kl + e];
        short8 hi, lo; cvt_hi_lo(x, hi, lo);
        unsigned* d0 = dst + (blk * nph + ph) * 4096 + wv * 1024 + step * 512 + lane * 4;
        union U { short8 s; uint4 u; };
        U uh, ul; uh.s = hi; ul.s = lo;
        *(uint4*)d0 = uh.u;
        *(uint4*)(d0 + 256) = ul.u;
    }
}

// ---- packed-W GEMM, BARRIER-FREE: wave-private ring-2 LDS (W 4KB + X 4KB
// per wave per buffer = 64KB/block). Each wave stages its OWN X copy so all
// deps are wave-local: counted vmcnt(8) + sched_barrier(0) only — no
// s_barrier, no compiler vmcnt(0) drain (the R9-R12 hidden serializer).
__global__ __launch_bounds__(256, 2) void k_gemmP(
        const unsigned* __restrict__ Xp, const unsigned* __restrict__ pk,
        float* __restrict__ part, int Nfull, int ntiles, int kc) {
    __shared__ char smem[2][4][8192];
    int wave = threadIdx.x >> 6, lane = threadIdx.x & 63;
    int tile = blockIdx.x % ntiles, split = blockIdx.x / ntiles;
    int k0 = split * kc;
    int m = lane & 31, half = lane >> 5;
    int nph = kc >> 5;
    const char* wsrc = (const char*)pk + (size_t)blockIdx.x * nph * 16384
                       + wave * 4096 + lane * 16;          // per-lane global src
    const char* xsrc = (const char*)Xp + (size_t)(k0 >> 4) * 2048 + lane * 16;

    auto stagef = [&](int ph) {
        char* base = &smem[ph & 1][wave][0];
        const char* wsp = wsrc + (size_t)ph * 16384;
        const char* xsp = xsrc + (size_t)ph * 4096;
        #pragma unroll
        for (int q = 0; q < 4; ++q)
            __builtin_amdgcn_global_load_lds((gv_t*)(wsp + q * 1024),
                                             (lv_t*)(base + q * 1024), 16, 0, 0);
        #pragma unroll
        for (int q = 0; q < 4; ++q)
            __builtin_amdgcn_global_load_lds((gv_t*)(xsp + q * 1024),
                                             (lv_t*)(base + 4096 + q * 1024), 16, 0, 0);
    };

    f32x16 acc;
    #pragma unroll
    for (int i = 0; i < 16; ++i) acc[i] = 0.f;

    stagef(0);
    stagef(1);
    union U { uint4 u; short8 s; };
    for (int ph = 0; ph < nph; ++ph) {
        if (ph + 1 < nph) { asm volatile("s_waitcnt vmcnt(8)" ::: "memory"); }
        else              { asm volatile("s_waitcnt vmcnt(0)" ::: "memory"); }
        __builtin_amdgcn_sched_barrier(0);
        const char* wb = &smem[ph & 1][wave][0];
        const char* xb = wb + 4096;
        #pragma unroll
        for (int st = 0; st < 2; ++st) {
            U ah, al, bh, bl;
            ah.u = *(const uint4*)(wb + st * 2048 + lane * 16);
            al.u = *(const uint4*)(wb + st * 2048 + 1024 + lane * 16);
            bh.u = *(const uint4*)(xb + st * 2048 + lane * 16);
            bl.u = *(const uint4*)(xb + st * 2048 + 1024 + lane * 16);
            acc = __builtin_amdgcn_mfma_f32_32x32x16_bf16(ah.s, bh.s, acc, 0, 0, 0);
            acc = __builtin_amdgcn_mfma_f32_32x32x16_bf16(ah.s, bl.s, acc, 0, 0, 0);
            acc = __builtin_amdgcn_mfma_f32_32x32x16_bf16(al.s, bh.s, acc, 0, 0, 0);
        }
        __builtin_amdgcn_sched_barrier(0);   // keep stage below the ds_reads/MFMAs
        if (ph + 2 < nph) stagef(ph + 2);
    }
    int n0 = tile * 128 + wave * 32;
    float* dst = part + (size_t)split * Nfull * TT + (size_t)n0 * TT + m;
    #pragma unroll
    for (int r = 0; r < 16; ++r) {
        int rr = (r & 3) + 8 * (r >> 2) + 4 * half;
        dst[(size_t)rr * TT] = acc[r];
    }
}

// ---- fallback GEMM (unpacked, R10 structure) ----
__global__ __launch_bounds__(256, 2) void k_gemm3(
        const unsigned* __restrict__ Xp, const float* __restrict__ W0,
        const float* __restrict__ W1, const float* __restrict__ W2,
        int t1, int t2, float* __restrict__ part,
        int Nfull, int K, int ntiles, int kc) {
    __shared__ char smem[3 * 20480];
    int wave = threadIdx.x >> 6, lane = threadIdx.x & 63;
    int tile = blockIdx.x % ntiles, split = blockIdx.x / ntiles;
    int k0 = split * kc;
    int m = lane & 31, half = lane >> 5;
    const float* Wsel; int rt;
    if (tile < t1)      { Wsel = W0; rt = tile; }
    else if (tile < t2) { Wsel = W1; rt = tile - t1; }
    else                { Wsel = W2; rt = tile - t2; }
    int r8 = lane >> 3;
    int s8 = lane & 7;
    const float* wsrc = Wsel + (size_t)(rt * 128 + wave * 32 + r8) * K + k0 + ((s8 ^ r8) << 2);
    const unsigned* xsrc = Xp + ((size_t)(k0 >> 4) + (wave >> 1)) * 512 + (wave & 1) * 256 + lane * 4;
    int nph = kc >> 5;

    auto stagef = [&](int ph) {
        char* buf = smem + (ph % 3) * 20480;
        const float* wsp = wsrc + (size_t)ph * 32;
        char* wdb = buf + wave * 4096;
        #pragma unroll
        for (int q = 0; q < 4; ++q)
            __builtin_amdgcn_global_load_lds((gv_t*)(wsp + (size_t)(q * 8) * K),
                                             (lv_t*)(wdb + q * 1024), 16, 0, 0);
        __builtin_amdgcn_global_load_lds((gv_t*)(xsrc + (size_t)ph * 1024),
                                         (lv_t*)(buf + 16384 + wave * 1024), 16, 0, 0);
    };

    f32x16 acc;
    #pragma unroll
    for (int i = 0; i < 16; ++i) acc[i] = 0.f;

    stagef(0);
    if (nph > 1) stagef(1);
    union U { uint4 u; short8 s; };
    for (int ph = 0; ph < nph; ++ph) {
        if (ph + 1 < nph) { asm volatile("s_waitcnt vmcnt(5)" ::: "memory"); }
        else              { asm volatile("s_waitcnt vmcnt(0)" ::: "memory"); }
        __builtin_amdgcn_sched_barrier(0);
        __syncthreads();
        const char* buf = smem + (ph % 3) * 20480;
        const char* wrow = buf + (wave * 32 + m) * 128;
        const char* xb = buf + 16384;
        #pragma unroll
        for (int st = 0; st < 2; ++st) {
            int t0 = st * 4 + half * 2;
            float4 wa = *(const float4*)(wrow + ((t0 ^ (m & 7)) << 4));
            float4 wb = *(const float4*)(wrow + (((t0 + 1) ^ (m & 7)) << 4));
            float xv[8] = {wa.x, wa.y, wa.z, wa.w, wb.x, wb.y, wb.z, wb.w};
            short8 whi, wlo;
            cvt_hi_lo(xv, whi, wlo);
            U bh, bl;
            bh.u = *(const uint4*)(xb + st * 2048 + lane * 16);
            bl.u = *(const uint4*)(xb + st * 2048 + 1024 + lane * 16);
            acc = __builtin_amdgcn_mfma_f32_32x32x16_bf16(whi, bh.s, acc, 0, 0, 0);
            acc = __builtin_amdgcn_mfma_f32_32x32x16_bf16(whi, bl.s, acc, 0, 0, 0);
            acc = __builtin_amdgcn_mfma_f32_32x32x16_bf16(wlo, bh.s, acc, 0, 0, 0);
        }
        if (ph + 2 < nph) stagef(ph + 2);
    }
    int n0 = tile * 128 + wave * 32;
    float* dst = part + (size_t)split * Nfull * TT + (size_t)n0 * TT + m;
    #pragma unroll
    for (int r = 0; r < 16; ++r) {
        int rr = (r & 3) + 8 * (r >> 2) + 4 * half;
        dst[(size_t)rr * TT] = acc[r];
    }
}

__global__ void k_reduce_qkv(const float* __restrict__ part, float* __restrict__ red,
                             int S) {
    int idx = blockIdx.x * 256 + threadIdx.x;
    float a = 0.f;
    for (int s = 0; s < S; ++s) a += part[(size_t)s * NQKV * TT + idx];
    red[idx] = a;
}

__global__ __launch_bounds__(64) void k_attn_f(const float* __restrict__ red,
        float* __restrict__ kcache, float* __restrict__ vcache,
        float* __restrict__ aoT, int p) {
    int t = blockIdx.x >> 5, h = blockIdx.x & 31, kvh = h >> 2;
    int d = threadIdx.x;
    float a  = red[(size_t)(h * HD + d) * TT + t];
    float b  = red[(size_t)(h * HD + d + 64) * TT + t];
    float ak = red[(size_t)(4096 + kvh * HD + d) * TT + t];
    float bk = red[(size_t)(4096 + kvh * HD + d + 64) * TT + t];
    float v0 = red[(size_t)(5120 + kvh * HD + d) * TT + t];
    float v1 = red[(size_t)(5120 + kvh * HD + d + 64) * TT + t];
    float fp = (float)p;
    float ang = fp * powf(500000.0f, -(float)d * (1.0f / 64.0f));
    float cs = cosf(ang), sn = sinf(ang);
    float q0 = a * cs - b * sn,  q1 = b * cs + a * sn;
    float k0r = ak * cs - bk * sn, k1r = bk * cs + ak * sn;
    if ((h & 3) == 0) {
        float* krow = kcache + (((size_t)t * SEQ + p) * NKV + kvh) * HD;
        krow[d] = k0r; krow[d + 64] = k1r;
        float* vrow = vcache + (((size_t)t * SEQ + p) * NKV + kvh) * HD;
        vrow[d] = v0; vrow[d + 64] = v1;
    }
    const float scale = 0.08838834764831845f;
    float sc[SEQ];
    float mx = -1e30f;
    #pragma unroll
    for (int j = 0; j < SEQ; ++j) {
        int jj = (j < p) ? j : p;
        float k0j, k1j;
        if (jj == p) { k0j = k0r; k1j = k1r; }
        else {
            const float* kr = kcache + (((size_t)t * SEQ + jj) * NKV + kvh) * HD;
            k0j = kr[d]; k1j = kr[d + 64];
        }
        float ps = q0 * k0j + q1 * k1j;
        #pragma unroll
        for (int mm = 1; mm < 64; mm <<= 1) ps += __shfl_xor(ps, mm);
        ps = (j <= p) ? ps * scale : -1e30f;
        sc[j] = ps;
        mx = fmaxf(mx, ps);
    }
    float denom = 0.f;
    #pragma unroll
    for (int j = 0; j < SEQ; ++j) {
        float e = expf(sc[j] - mx);
        e = (j <= p) ? e : 0.f;
        sc[j] = e; denom += e;
    }
    float inv = 1.0f / denom;
    float o0 = 0.f, o1 = 0.f;
    #pragma unroll
    for (int j = 0; j < SEQ; ++j) {
        int jj = (j < p) ? j : p;
        float vv0, vv1;
        if (jj == p) { vv0 = v0; vv1 = v1; }
        else {
            const float* vr = vcache + (((size_t)t * SEQ + jj) * NKV + kvh) * HD;
            vv0 = vr[d]; vv1 = vr[d + 64];
        }
        float w = sc[j] * inv;
        o0 = fmaf(w, vv0, o0);
        o1 = fmaf(w, vv1, o1);
    }
    aoT[(size_t)(h * HD + d) * TT + t] = o0;
    aoT[(size_t)(h * HD + d + 64) * TT + t] = o1;
}

__global__ void k_reduce_o(const float* __restrict__ part, const float* __restrict__ buf,
                           float* __restrict__ xp, int p, int S) {
    int idx = blockIdx.x * 256 + threadIdx.x;
    int n = idx >> 5, t = idx & 31;
    float a = 0.f;
    for (int s = 0; s < S; ++s) a += part[(size_t)s * D * TT + idx];
    xp[(size_t)t * D + n] = a + buf[((size_t)t * SEQ + p) * D + n];
}

__global__ __launch_bounds__(256) void k_silu_pack(const float* __restrict__ part,
        unsigned* __restrict__ Xp, int S) {
    int frag = blockIdx.x * 4 + (threadIdx.x >> 6);
    int lane = threadIdx.x & 63;
    int m = lane & 31, half = lane >> 5;
    int n0 = frag * 16 + half * 8;
    float x[8];
    #pragma unroll
    for (int e = 0; e < 8; ++e) {
        int n = n0 + e;
        float g = 0.f, u = 0.f;
        for (int s = 0; s < S; ++s) {
            const float* pb = part + (size_t)s * NGU * TT;
            g += pb[(size_t)n * TT + m];
            u += pb[(size_t)(n + FF) * TT + m];
        }
        float sg = g / (1.0f + expf(-g));
        x[e] = sg * u;
    }
    short8 hi, lo; cvt_hi_lo(x, hi, lo); store_frag(Xp, frag, lane, hi, lo);
}

__global__ __launch_bounds__(256) void k_reduced_pack(const float* __restrict__ part,
        const float* __restrict__ xp, unsigned* __restrict__ Xp, int S) {
    int frag = blockIdx.x * 4 + (threadIdx.x >> 6);
    int lane = threadIdx.x & 63;
    int m = lane & 31, half = lane >> 5;
    int n0 = frag * 16 + half * 8;
    float x[8];
    #pragma unroll
    for (int e = 0; e < 8; ++e) {
        int n = n0 + e;
        float a = 0.f;
        for (int s = 0; s < S; ++s)
            a += part[(size_t)s * D * TT + (size_t)n * TT + m];
        x[e] = a + xp[(size_t)m * D + n];
    }
    short8 hi, lo; cvt_hi_lo(x, hi, lo); store_frag(Xp, frag, lane, hi, lo);
}

__global__ void k_logits_reduce(const float* __restrict__ part,
                                const float* __restrict__ bias,
                                float* __restrict__ lr, int S) {
    int idx = blockIdx.x * 256 + threadIdx.x;
    int n = idx >> 5;
    float a = bias[n];
    for (int s = 0; s < S; ++s) a += part[(size_t)s * VOC * TT + idx];
    lr[idx] = a;
}

__global__ void k_head(const float* __restrict__ lr, const float* __restrict__ emb,
                       int* __restrict__ toks, float* __restrict__ buf,
                       float* __restrict__ r1, int p) {
    int t = blockIdx.x;
    int tid = threadIdx.x;
    float bv = -1e30f; int bi = 0;
    for (int n = tid; n < VOC; n += 256) {
        float a = lr[(size_t)n * TT + t];
        if (a > bv) { bv = a; bi = n; }
    }
    __shared__ float sv[256];
    __shared__ int si[256];
    sv[tid] = bv; si[tid] = bi;
    __syncthreads();
    for (int off = 128; off > 0; off >>= 1) {
        if (tid < off) {
            float v2 = sv[tid + off]; int i2 = si[tid + off];
            if (v2 > sv[tid] || (v2 == sv[tid] && i2 < si[tid])) { sv[tid] = v2; si[tid] = i2; }
        }
        __syncthreads();
    }
    int tok = si[0];
    if (tid == 0) toks[t * GENN + p] = tok;
    const float* er = emb + (size_t)tok * D;
    float* brow = buf + ((size_t)t * SEQ + (p + 1)) * D;
    float ss = 0.f;
    for (int d = tid; d < D; d += 256) { float v = er[d]; brow[d] = v; ss += v * v; }
    #pragma unroll
    for (int m = 1; m < 64; m <<= 1) ss += __shfl_xor(ss, m);
    __shared__ float red[4];
    if ((tid & 63) == 0) red[tid >> 6] = ss;
    __syncthreads();
    if (tid == 0) {
        float tot = red[0] + red[1] + red[2] + red[3];
        r1[t] = 1.0f / sqrtf(tot / (float)D + 1e-5f);
    }
}

extern "C" void kernel_launch(void* const* d_in, const int* in_sizes, int n_in,
                              void* d_out, int out_size, void* d_ws, size_t ws_size,
                              hipStream_t stream) {
    const float* x0   = (const float*)d_in[0];
    const float* Wq   = (const float*)d_in[1];
    const float* Wk   = (const float*)d_in[2];
    const float* Wv   = (const float*)d_in[3];
    const float* Wo   = (const float*)d_in[4];
    const float* wln1 = (const float*)d_in[5];
    const float* wln2 = (const float*)d_in[6];
    const float* Wg   = (const float*)d_in[7];
    const float* Wu   = (const float*)d_in[8];
    const float* Wd   = (const float*)d_in[9];
    const float* emb  = (const float*)d_in[11];
    const float* Wout = (const float*)d_in[12];
    const float* bout = (const float*)d_in[13];

    float* ws   = (float*)d_ws;
    float* buf  = ws + OFF_BUF;
    float* kcc  = ws + OFF_KC;
    float* vcc  = ws + OFF_VC;
    float* aoT  = ws + OFF_AOT;
    float* xp   = ws + OFF_XP;
    float* r1   = ws + OFF_R1;
    float* r2   = ws + OFF_R2;
    unsigned* Xpk = (unsigned*)(ws + OFF_XPK);
    float* part = ws + OFF_PART;
    float* redq = ws + OFF_RED;
    float* lr   = ws + OFF_LR;
    unsigned* pk = (unsigned*)(ws + OFF_PACK);

    const bool packed = (ws_size / 4) >= (OFF_PACK + PK_TOTAL);

    size_t availF = 4194304;
    auto fitS = [&](int smax, size_t cols, int K) {
        int s = smax;
        while (s > 1 && (size_t)s * cols * TT > availF) s >>= 1;
        while (s > 1 && (((K / s) % 32) || (K / s) < 64)) s >>= 1;
        return s;
    };
    const int S_qkv = fitS(16, NQKV, D);   // 16, kc 256
    const int S_wo  = fitS(16, D, D);      // 16, kc 256
    const int S_gu  = fitS(4,  NGU, D);    // 4,  kc 1024
    const int S_wd  = fitS(16, D, FF);     // 16, kc 896
    const int S_out = fitS(64, VOC, D);    // 64, kc 64
    const int kc_qkv = D / S_qkv;
    const int kc_wo  = D / S_wo;
    const int kc_gu  = D / S_gu;
    const int kc_wd  = FF / S_wd;
    const int kc_out = D / S_out;
    const int BIG = 1 << 20;

    if (packed) {
        k_pack_w<<<S_qkv * 32 * (kc_qkv / 32), 256, 0, stream>>>(Wq, pk + PK_QKV, D, kc_qkv, kc_qkv / 32, 48, 0, 32);
        k_pack_w<<<S_qkv * 8  * (kc_qkv / 32), 256, 0, stream>>>(Wk, pk + PK_QKV, D, kc_qkv, kc_qkv / 32, 48, 32, 8);
        k_pack_w<<<S_qkv * 8  * (kc_qkv / 32), 256, 0, stream>>>(Wv, pk + PK_QKV, D, kc_qkv, kc_qkv / 32, 48, 40, 8);
        k_pack_w<<<S_wo * 32 * (kc_wo / 32), 256, 0, stream>>>(Wo, pk + PK_WO, D, kc_wo, kc_wo / 32, 32, 0, 32);
        k_pack_w<<<S_gu * 112 * (kc_gu / 32), 256, 0, stream>>>(Wg, pk + PK_GU, D, kc_gu, kc_gu / 32, 224, 0, 112);
        k_pack_w<<<S_gu * 112 * (kc_gu / 32), 256, 0, stream>>>(Wu, pk + PK_GU, D, kc_gu, kc_gu / 32, 224, 112, 112);
        k_pack_w<<<S_wd * 32 * (kc_wd / 32), 256, 0, stream>>>(Wd, pk + PK_WD, FF, kc_wd, kc_wd / 32, 32, 0, 32);
        k_pack_w<<<S_out * 8 * (kc_out / 32), 256, 0, stream>>>(Wout, pk + PK_OUT, D, kc_out, kc_out / 32, 8, 0, 8);
    }

    k_init<<<32, 256, 0, stream>>>(x0, buf, r1);
    for (int p = 0; p < GENN; ++p) {
        k_pack_norm<<<64, 256, 0, stream>>>(buf + (size_t)p * D, SEQ * D, r1, wln1, Xpk);
        if (packed)
            k_gemmP<<<48 * S_qkv, 256, 0, stream>>>(Xpk, pk + PK_QKV, part, NQKV, 48, kc_qkv);
        else
            k_gemm3<<<48 * S_qkv, 256, 0, stream>>>(Xpk, Wq, Wk, Wv, 32, 40,
                                                    part, NQKV, D, 48, kc_qkv);
        k_reduce_qkv<<<NQKV * TT / 256, 256, 0, stream>>>(part, redq, S_qkv);
        k_attn_f<<<1024, 64, 0, stream>>>(redq, kcc, vcc, aoT, p);
        k_pack<<<64, 256, 0, stream>>>(aoT, Xpk);
        if (packed)
            k_gemmP<<<32 * S_wo, 256, 0, stream>>>(Xpk, pk + PK_WO, part, D, 32, kc_wo);
        else
            k_gemm3<<<32 * S_wo, 256, 0, stream>>>(Xpk, Wo, Wo, Wo, BIG, BIG,
                                                   part, D, D, 32, kc_wo);
        k_reduce_o<<<512, 256, 0, stream>>>(part, buf, xp, p, S_wo);
        k_rms_rows<<<32, 256, 0, stream>>>(xp, r2);
        k_pack_norm<<<64, 256, 0, stream>>>(xp, D, r2, wln2, Xpk);
        if (packed)
            k_gemmP<<<224 * S_gu, 256, 0, stream>>>(Xpk, pk + PK_GU, part, NGU, 224, kc_gu);
        else
            k_gemm3<<<224 * S_gu, 256, 0, stream>>>(Xpk, Wg, Wu, Wu, 112, BIG,
                                                    part, NGU, D, 224, kc_gu);
        k_silu_pack<<<224, 256, 0, stream>>>(part, Xpk, S_gu);
        if (packed)
            k_gemmP<<<32 * S_wd, 256, 0, stream>>>(Xpk, pk + PK_WD, part, D, 32, kc_wd);
        else
            k_gemm3<<<32 * S_wd, 256, 0, stream>>>(Xpk, Wd, Wd, Wd, BIG, BIG,
                                                   part, D, FF, 32, kc_wd);
        k_reduced_pack<<<64, 256, 0, stream>>>(part, xp, Xpk, S_wd);
        if (packed)
            k_gemmP<<<8 * S_out, 256, 0, stream>>>(Xpk, pk + PK_OUT, part, VOC, 8, kc_out);
        else
            k_gemm3<<<8 * S_out, 256, 0, stream>>>(Xpk, Wout, Wout, Wout, BIG, BIG,
                                                   part, VOC, D, 8, kc_out);
        k_logits_reduce<<<VOC * TT / 256, 256, 0, stream>>>(part, bout, lr, S_out);
        k_head<<<32, 256, 0, stream>>>(lr, emb, (int*)d_out, buf, r1, p);
    }
}

// Round 14
// 2448.062 us; speedup vs baseline: 1.1115x; 1.1115x over previous
//
#include <hip/hip_runtime.h>
#include <hip/hip_bf16.h>

#define D 4096
#define NH 32
#define NKV 8
#define HD 128
#define FF 14336
#define VOC 1024
#define TT 32
#define GENN 8
#define SEQ 9

#define NQKV 6144   // fused QKV cols: 4096 Q + 1024 K + 1024 V
#define NGU  28672  // fused gate+up cols

// workspace offsets (floats)
#define OFF_BUF   0ull
#define OFF_KC    1179648ull
#define OFF_VC    1474560ull
#define OFF_AOT   1769472ull
#define OFF_XP    1900544ull
#define OFF_R1    2031616ull
#define OFF_R2    2031680ull
#define OFF_XPK   2031744ull
#define OFF_PART  2490496ull
#define OFF_RED   6684800ull   // NQKV*TT reduced QKV
#define OFF_LR    6881408ull   // VOC*TT reduced logits

typedef __attribute__((ext_vector_type(8))) short short8;
typedef __attribute__((ext_vector_type(16))) float f32x16;
typedef __attribute__((address_space(1))) void gv_t;
typedef __attribute__((address_space(3))) void lv_t;

__device__ inline void cvt_hi_lo(const float* x, short8& hi, short8& lo) {
    union U { unsigned u[4]; short8 s; };
    U H, L;
    #pragma unroll
    for (int j = 0; j < 4; ++j) {
        float2 p = make_float2(x[2 * j], x[2 * j + 1]);
        __hip_bfloat162 h = __float22bfloat162_rn(p);
        unsigned hb; __builtin_memcpy(&hb, &h, 4);
        H.u[j] = hb;
        float f0 = __uint_as_float(hb << 16);
        float f1 = __uint_as_float(hb & 0xffff0000u);
        __hip_bfloat162 l = __float22bfloat162_rn(make_float2(p.x - f0, p.y - f1));
        unsigned lb; __builtin_memcpy(&lb, &l, 4);
        L.u[j] = lb;
    }
    hi = H.s; lo = L.s;
}

__device__ inline void store_frag(unsigned* Xp, int frag, int lane,
                                  const short8& hi, const short8& lo) {
    unsigned* dst = Xp + (size_t)frag * 512 + lane * 4;
    union U { short8 s; uint4 u; };
    U uh, ul; uh.s = hi; ul.s = lo;
    *(uint4*)dst = uh.u;
    *(uint4*)(dst + 256) = ul.u;
}

__global__ void k_init(const float* __restrict__ x0, float* __restrict__ buf,
                       float* __restrict__ r1) {
    int t = blockIdx.x;
    const float* src = x0 + (size_t)t * D;
    float* dst = buf + (size_t)t * SEQ * D;
    float ss = 0.f;
    for (int d = threadIdx.x; d < D; d += 256) { float v = src[d]; dst[d] = v; ss += v * v; }
    #pragma unroll
    for (int m = 1; m < 64; m <<= 1) ss += __shfl_xor(ss, m);
    __shared__ float red[4];
    if ((threadIdx.x & 63) == 0) red[threadIdx.x >> 6] = ss;
    __syncthreads();
    if (threadIdx.x == 0) {
        float tot = red[0] + red[1] + red[2] + red[3];
        r1[t] = 1.0f / sqrtf(tot / (float)D + 1e-5f);
    }
}

__global__ void k_rms_rows(const float* __restrict__ x, float* __restrict__ r) {
    int t = blockIdx.x;
    const float* row = x + (size_t)t * D;
    float ss = 0.f;
    for (int d = threadIdx.x; d < D; d += 256) { float v = row[d]; ss += v * v; }
    #pragma unroll
    for (int m = 1; m < 64; m <<= 1) ss += __shfl_xor(ss, m);
    __shared__ float red[4];
    if ((threadIdx.x & 63) == 0) red[threadIdx.x >> 6] = ss;
    __syncthreads();
    if (threadIdx.x == 0) {
        float tot = red[0] + red[1] + red[2] + red[3];
        r[t] = 1.0f / sqrtf(tot / (float)D + 1e-5f);
    }
}

__global__ __launch_bounds__(256) void k_pack_norm(const float* __restrict__ src0,
        int rowStride, const float* __restrict__ r, const float* __restrict__ w,
        unsigned* __restrict__ Xp) {
    int frag = blockIdx.x * 4 + (threadIdx.x >> 6);
    int lane = threadIdx.x & 63;
    int m = lane & 31, half = lane >> 5;
    int k0 = frag * 16 + half * 8;
    const float* src = src0 + (size_t)m * rowStride + k0;
    float rr = r[m];
    float x[8];
    #pragma unroll
    for (int e = 0; e < 8; ++e) x[e] = src[e] * rr * w[k0 + e];
    short8 hi, lo; cvt_hi_lo(x, hi, lo); store_frag(Xp, frag, lane, hi, lo);
}

__global__ __launch_bounds__(256) void k_pack(const float* __restrict__ XT,
                                              unsigned* __restrict__ Xp) {
    int frag = blockIdx.x * 4 + (threadIdx.x >> 6);
    int lane = threadIdx.x & 63;
    int m = lane & 31, half = lane >> 5;
    const float* src = XT + (size_t)(frag * 16 + half * 8) * TT + m;
    float x[8];
    #pragma unroll
    for (int e = 0; e < 8; ++e) x[e] = src[e * TT];
    short8 hi, lo; cvt_hi_lo(x, hi, lo); store_frag(Xp, frag, lane, hi, lo);
}

// part[s][n][m] over split k-range of X[m][k]*W[n][k], bf16x3 MFMA.
// Ring-3 LDS pipeline with counted vmcnt (R10 structure, measured best).
__global__ __launch_bounds__(256, 2) void k_gemm3(
        const unsigned* __restrict__ Xp, const float* __restrict__ W0,
        const float* __restrict__ W1, const float* __restrict__ W2,
        int t1, int t2, float* __restrict__ part,
        int Nfull, int K, int ntiles, int kc) {
    __shared__ char smem[3 * 20480];   // per buffer: 16KB W (128x128B) + 4KB X
    int wave = threadIdx.x >> 6, lane = threadIdx.x & 63;
    int tile = blockIdx.x % ntiles, split = blockIdx.x / ntiles;
    int k0 = split * kc;
    int m = lane & 31, half = lane >> 5;
    const float* Wsel; int rt;
    if (tile < t1)      { Wsel = W0; rt = tile; }
    else if (tile < t2) { Wsel = W1; rt = tile - t1; }
    else                { Wsel = W2; rt = tile - t2; }
    int r8 = lane >> 3;          // staged row within 8-row chunk; == (row & 7)
    int s8 = lane & 7;           // physical 16B slot
    // pre-swizzled global source: LDS phys slot s8 of row r holds logical slot s8 ^ (r&7)
    const float* wsrc = Wsel + (size_t)(rt * 128 + wave * 32 + r8) * K + k0 + ((s8 ^ r8) << 2);
    // X: wave w stages frag-rel (w>>1), half (w&1): 1KB contiguous
    const unsigned* xsrc = Xp + ((size_t)(k0 >> 4) + (wave >> 1)) * 512 + (wave & 1) * 256 + lane * 4;
    int nph = kc >> 5;

    auto stagef = [&](int ph) {
        char* buf = smem + (ph % 3) * 20480;
        const float* wsp = wsrc + (size_t)ph * 32;
        char* wdb = buf + wave * 4096;          // wave-uniform LDS base
        #pragma unroll
        for (int q = 0; q < 4; ++q) {
            __builtin_amdgcn_global_load_lds(
                (gv_t*)(wsp + (size_t)(q * 8) * K),
                (lv_t*)(wdb + q * 1024), 16, 0, 0);
        }
        __builtin_amdgcn_global_load_lds(
            (gv_t*)(xsrc + (size_t)ph * 1024),
            (lv_t*)(buf + 16384 + wave * 1024), 16, 0, 0);
    };

    f32x16 acc;
    #pragma unroll
    for (int i = 0; i < 16; ++i) acc[i] = 0.f;

    stagef(0);
    if (nph > 1) stagef(1);
    union U { uint4 u; short8 s; };
    for (int ph = 0; ph < nph; ++ph) {
        if (ph + 1 < nph) { asm volatile("s_waitcnt vmcnt(5)" ::: "memory"); }
        else              { asm volatile("s_waitcnt vmcnt(0)" ::: "memory"); }
        __builtin_amdgcn_sched_barrier(0);
        __syncthreads();
        const char* buf = smem + (ph % 3) * 20480;
        const char* wrow = buf + (wave * 32 + m) * 128;
        const char* xb = buf + 16384;
        #pragma unroll
        for (int st = 0; st < 2; ++st) {
            int t0 = st * 4 + half * 2;
            float4 wa = *(const float4*)(wrow + ((t0 ^ (m & 7)) << 4));
            float4 wb = *(const float4*)(wrow + (((t0 + 1) ^ (m & 7)) << 4));
            float xv[8] = {wa.x, wa.y, wa.z, wa.w, wb.x, wb.y, wb.z, wb.w};
            short8 whi, wlo;
            cvt_hi_lo(xv, whi, wlo);
            U bh, bl;
            bh.u = *(const uint4*)(xb + st * 2048 + lane * 16);
            bl.u = *(const uint4*)(xb + st * 2048 + 1024 + lane * 16);
            acc = __builtin_amdgcn_mfma_f32_32x32x16_bf16(whi, bh.s, acc, 0, 0, 0);
            acc = __builtin_amdgcn_mfma_f32_32x32x16_bf16(whi, bl.s, acc, 0, 0, 0);
            acc = __builtin_amdgcn_mfma_f32_32x32x16_bf16(wlo, bh.s, acc, 0, 0, 0);
        }
        if (ph + 2 < nph) stagef(ph + 2);
    }
    int n0 = tile * 128 + wave * 32;
    float* dst = part + (size_t)split * Nfull * TT + (size_t)n0 * TT + m;
    #pragma unroll
    for (int r = 0; r < 16; ++r) {
        int rr = (r & 3) + 8 * (r >> 2) + 4 * half;
        dst[(size_t)rr * TT] = acc[r];
    }
}

// COALESCED pre-reduction of QKV partials: red[idx] = sum_s part[s][idx]
__global__ void k_reduce_qkv(const float* __restrict__ part, float* __restrict__ red,
                             int S) {
    int idx = blockIdx.x * 256 + threadIdx.x;   // NQKV*TT
    float a = 0.f;
    for (int s = 0; s < S; ++s) a += part[(size_t)s * NQKV * TT + idx];
    red[idx] = a;
}

// attention finish reading the small reduced buffer (L2-resident)
__global__ __launch_bounds__(64) void k_attn_f(const float* __restrict__ red,
        float* __restrict__ kcache, float* __restrict__ vcache,
        float* __restrict__ aoT, int p) {
    int t = blockIdx.x >> 5, h = blockIdx.x & 31, kvh = h >> 2;
    int d = threadIdx.x;
    float a  = red[(size_t)(h * HD + d) * TT + t];
    float b  = red[(size_t)(h * HD + d + 64) * TT + t];
    float ak = red[(size_t)(4096 + kvh * HD + d) * TT + t];
    float bk = red[(size_t)(4096 + kvh * HD + d + 64) * TT + t];
    float v0 = red[(size_t)(5120 + kvh * HD + d) * TT + t];
    float v1 = red[(size_t)(5120 + kvh * HD + d + 64) * TT + t];
    float fp = (float)p;
    float ang = fp * powf(500000.0f, -(float)d * (1.0f / 64.0f));
    float cs = cosf(ang), sn = sinf(ang);
    float q0 = a * cs - b * sn,  q1 = b * cs + a * sn;
    float k0r = ak * cs - bk * sn, k1r = bk * cs + ak * sn;
    if ((h & 3) == 0) {
        float* krow = kcache + (((size_t)t * SEQ + p) * NKV + kvh) * HD;
        krow[d] = k0r; krow[d + 64] = k1r;
        float* vrow = vcache + (((size_t)t * SEQ + p) * NKV + kvh) * HD;
        vrow[d] = v0; vrow[d + 64] = v1;
    }
    const float scale = 0.08838834764831845f;  // 1/sqrt(128)
    float sc[SEQ];
    float mx = -1e30f;
    #pragma unroll
    for (int j = 0; j < SEQ; ++j) {
        int jj = (j < p) ? j : p;
        float k0j, k1j;
        if (jj == p) { k0j = k0r; k1j = k1r; }
        else {
            const float* kr = kcache + (((size_t)t * SEQ + jj) * NKV + kvh) * HD;
            k0j = kr[d]; k1j = kr[d + 64];
        }
        float ps = q0 * k0j + q1 * k1j;
        #pragma unroll
        for (int mm = 1; mm < 64; mm <<= 1) ps += __shfl_xor(ps, mm);
        ps = (j <= p) ? ps * scale : -1e30f;
        sc[j] = ps;
        mx = fmaxf(mx, ps);
    }
    float denom = 0.f;
    #pragma unroll
    for (int j = 0; j < SEQ; ++j) {
        float e = expf(sc[j] - mx);
        e = (j <= p) ? e : 0.f;
        sc[j] = e; denom += e;
    }
    float inv = 1.0f / denom;
    float o0 = 0.f, o1 = 0.f;
    #pragma unroll
    for (int j = 0; j < SEQ; ++j) {
        int jj = (j < p) ? j : p;
        float vv0, vv1;
        if (jj == p) { vv0 = v0; vv1 = v1; }
        else {
            const float* vr = vcache + (((size_t)t * SEQ + jj) * NKV + kvh) * HD;
            vv0 = vr[d]; vv1 = vr[d + 64];
        }
        float w = sc[j] * inv;
        o0 = fmaf(w, vv0, o0);
        o1 = fmaf(w, vv1, o1);
    }
    aoT[(size_t)(h * HD + d) * TT + t] = o0;
    aoT[(size_t)(h * HD + d + 64) * TT + t] = o1;
}

// part layout [s][n][TT]; xp[t][D] = sum_s part + residual  (coalesced reads)
__global__ void k_reduce_o(const float* __restrict__ part, const float* __restrict__ buf,
                           float* __restrict__ xp, int p, int S) {
    int idx = blockIdx.x * 256 + threadIdx.x;   // D*32
    int n = idx >> 5, t = idx & 31;
    float a = 0.f;
    for (int s = 0; s < S; ++s) a += part[(size_t)s * D * TT + idx];
    xp[(size_t)t * D + n] = a + buf[((size_t)t * SEQ + p) * D + n];
}

// fused: reduce gate+up partials, silu*u, pack fragments (K = FF)
__global__ __launch_bounds__(256) void k_silu_pack(const float* __restrict__ part,
        unsigned* __restrict__ Xp, int S) {
    int frag = blockIdx.x * 4 + (threadIdx.x >> 6);   // FF/16 frags
    int lane = threadIdx.x & 63;
    int m = lane & 31, half = lane >> 5;
    int n0 = frag * 16 + half * 8;
    float x[8];
    #pragma unroll
    for (int e = 0; e < 8; ++e) {
        int n = n0 + e;
        float g = 0.f, u = 0.f;
        for (int s = 0; s < S; ++s) {
            const float* pb = part + (size_t)s * NGU * TT;
            g += pb[(size_t)n * TT + m];
            u += pb[(size_t)(n + FF) * TT + m];
        }
        float sg = g / (1.0f + expf(-g));
        x[e] = sg * u;
    }
    short8 hi, lo; cvt_hi_lo(x, hi, lo); store_frag(Xp, frag, lane, hi, lo);
}

// fused: reduce Wd partials + residual, pack fragments for head GEMM (K = D)
__global__ __launch_bounds__(256) void k_reduced_pack(const float* __restrict__ part,
        const float* __restrict__ xp, unsigned* __restrict__ Xp, int S) {
    int frag = blockIdx.x * 4 + (threadIdx.x >> 6);   // D/16 frags
    int lane = threadIdx.x & 63;
    int m = lane & 31, half = lane >> 5;
    int n0 = frag * 16 + half * 8;
    float x[8];
    #pragma unroll
    for (int e = 0; e < 8; ++e) {
        int n = n0 + e;
        float a = 0.f;
        for (int s = 0; s < S; ++s)
            a += part[(size_t)s * D * TT + (size_t)n * TT + m];
        x[e] = a + xp[(size_t)m * D + n];
    }
    short8 hi, lo; cvt_hi_lo(x, hi, lo); store_frag(Xp, frag, lane, hi, lo);
}

// COALESCED logits reduction: lr[idx] = bias[n] + sum_s part[s][idx]
__global__ void k_logits_reduce(const float* __restrict__ part,
                                const float* __restrict__ bias,
                                float* __restrict__ lr, int S) {
    int idx = blockIdx.x * 256 + threadIdx.x;   // VOC*TT
    int n = idx >> 5;
    float a = bias[n];
    for (int s = 0; s < S; ++s) a += part[(size_t)s * VOC * TT + idx];
    lr[idx] = a;
}

// argmax over reduced logits, write token, write buf row p+1 = emb[tok], compute r1
__global__ void k_head(const float* __restrict__ lr, const float* __restrict__ emb,
                       int* __restrict__ toks, float* __restrict__ buf,
                       float* __restrict__ r1, int p) {
    int t = blockIdx.x;
    int tid = threadIdx.x;
    float bv = -1e30f; int bi = 0;
    for (int n = tid; n < VOC; n += 256) {
        float a = lr[(size_t)n * TT + t];
        if (a > bv) { bv = a; bi = n; }   // ascending n -> first max kept
    }
    __shared__ float sv[256];
    __shared__ int si[256];
    sv[tid] = bv; si[tid] = bi;
    __syncthreads();
    for (int off = 128; off > 0; off >>= 1) {
        if (tid < off) {
            float v2 = sv[tid + off]; int i2 = si[tid + off];
            if (v2 > sv[tid] || (v2 == sv[tid] && i2 < si[tid])) { sv[tid] = v2; si[tid] = i2; }
        }
        __syncthreads();
    }
    int tok = si[0];
    if (tid == 0) toks[t * GENN + p] = tok;
    const float* er = emb + (size_t)tok * D;
    float* brow = buf + ((size_t)t * SEQ + (p + 1)) * D;
    float ss = 0.f;
    for (int d = tid; d < D; d += 256) { float v = er[d]; brow[d] = v; ss += v * v; }
    #pragma unroll
    for (int m = 1; m < 64; m <<= 1) ss += __shfl_xor(ss, m);
    __shared__ float red[4];
    if ((tid & 63) == 0) red[tid >> 6] = ss;
    __syncthreads();
    if (tid == 0) {
        float tot = red[0] + red[1] + red[2] + red[3];
        r1[t] = 1.0f / sqrtf(tot / (float)D + 1e-5f);
    }
}

extern "C" void kernel_launch(void* const* d_in, const int* in_sizes, int n_in,
                              void* d_out, int out_size, void* d_ws, size_t ws_size,
                              hipStream_t stream) {
    const float* x0   = (const float*)d_in[0];
    const float* Wq   = (const float*)d_in[1];
    const float* Wk   = (const float*)d_in[2];
    const float* Wv   = (const float*)d_in[3];
    const float* Wo   = (const float*)d_in[4];
    const float* wln1 = (const float*)d_in[5];
    const float* wln2 = (const float*)d_in[6];
    const float* Wg   = (const float*)d_in[7];
    const float* Wu   = (const float*)d_in[8];
    const float* Wd   = (const float*)d_in[9];
    const float* emb  = (const float*)d_in[11];
    const float* Wout = (const float*)d_in[12];
    const float* bout = (const float*)d_in[13];

    float* ws   = (float*)d_ws;
    float* buf  = ws + OFF_BUF;
    float* kcc  = ws + OFF_KC;
    float* vcc  = ws + OFF_VC;
    float* aoT  = ws + OFF_AOT;
    float* xp   = ws + OFF_XP;
    float* r1   = ws + OFF_R1;
    float* r2   = ws + OFF_R2;
    unsigned* Xpk = (unsigned*)(ws + OFF_XPK);
    float* part = ws + OFF_PART;
    float* redq = ws + OFF_RED;
    float* lr   = ws + OFF_LR;

    size_t availF = 4194304;
    // kc % 32 == 0 (full BK phases) and kc >= 64 (>= 2 phases)
    auto fitS = [&](int smax, size_t cols, int K) {
        int s = smax;
        while (s > 1 && (size_t)s * cols * TT > availF) s >>= 1;
        while (s > 1 && (((K / s) % 32) || (K / s) < 64)) s >>= 1;
        return s;
    };
    const int S_qkv = fitS(16, NQKV, D);   // kc 256, grid 768
    const int S_wo  = fitS(16, D, D);      // kc 256, grid 512
    const int S_gu  = fitS(4,  NGU, D);    // kc 1024, grid 896
    const int S_wd  = fitS(16, D, FF);     // kc 896, grid 512
    const int S_out = fitS(64, VOC, D);    // kc 64,  grid 512
    const int kc_qkv = D / S_qkv;
    const int kc_wo  = D / S_wo;
    const int kc_gu  = D / S_gu;
    const int kc_wd  = FF / S_wd;
    const int kc_out = D / S_out;
    const int BIG = 1 << 20;

    k_init<<<32, 256, 0, stream>>>(x0, buf, r1);
    for (int p = 0; p < GENN; ++p) {
        k_pack_norm<<<64, 256, 0, stream>>>(buf + (size_t)p * D, SEQ * D, r1, wln1, Xpk);
        // fused QKV GEMM: 128-row tiles [0,32)=Wq, [32,40)=Wk, [40,48)=Wv
        k_gemm3<<<48 * S_qkv, 256, 0, stream>>>(Xpk, Wq, Wk, Wv, 32, 40,
                                                part, NQKV, D, 48, kc_qkv);
        k_reduce_qkv<<<NQKV * TT / 256, 256, 0, stream>>>(part, redq, S_qkv);
        k_attn_f<<<1024, 64, 0, stream>>>(redq, kcc, vcc, aoT, p);
        k_pack<<<64, 256, 0, stream>>>(aoT, Xpk);
        k_gemm3<<<32 * S_wo, 256, 0, stream>>>(Xpk, Wo, Wo, Wo, BIG, BIG,
                                               part, D, D, 32, kc_wo);
        k_reduce_o<<<512, 256, 0, stream>>>(part, buf, xp, p, S_wo);
        k_rms_rows<<<32, 256, 0, stream>>>(xp, r2);
        k_pack_norm<<<64, 256, 0, stream>>>(xp, D, r2, wln2, Xpk);
        // fused gate+up GEMM: tiles [0,112)=Wg, [112,224)=Wu
        k_gemm3<<<224 * S_gu, 256, 0, stream>>>(Xpk, Wg, Wu, Wu, 112, BIG,
                                                part, NGU, D, 224, kc_gu);
        k_silu_pack<<<224, 256, 0, stream>>>(part, Xpk, S_gu);
        k_gemm3<<<32 * S_wd, 256, 0, stream>>>(Xpk, Wd, Wd, Wd, BIG, BIG,
                                               part, D, FF, 32, kc_wd);
        k_reduced_pack<<<64, 256, 0, stream>>>(part, xp, Xpk, S_wd);
        k_gemm3<<<8 * S_out, 256, 0, stream>>>(Xpk, Wout, Wout, Wout, BIG, BIG,
                                               part, VOC, D, 8, kc_out);
        k_logits_reduce<<<VOC * TT / 256, 256, 0, stream>>>(part, bout, lr, S_out);
        k_head<<<32, 256, 0, stream>>>(lr, emb, (int*)d_out, buf, r1, p);
    }
}